// Round 8
// baseline (112.731 us; speedup 1.0000x reference)
//
#include <hip/hip_runtime.h>
#include <math.h>

// LIF forward scan: v = v*decay*(1-z_prev) + x_t ; z = (v > 0.5)
// B=256, T=1000, H=256. One block (256 thr = 4 waves) per batch row.
// Deep LDS ring: BATCH=20 rows/slot, RING=7 (140KB), DEPTH=6 -> 120KB/CU of
// reads in flight. Stores packed 4x via an LDS transpose that is software-
// pipelined 2 groups behind the compute (DS pipe is in-order per wave), so
// per-wave VMEM ops/iter = 5 glds + 5 stores -> precise vmcnt waits.
constexpr int T_LEN  = 1000;
constexpr int H_DIM  = 256;
constexpr int BATCH  = 20;                // rows per slot (20 KB)
constexpr int NBATCH = T_LEN / BATCH;     // 50
constexpr int RING   = 7;                 // X ring slots (140 KB)
constexpr int DEPTH  = 6;                 // slots prefetched ahead
constexpr int RPW    = BATCH / 4;         // rows staged per wave = 5
constexpr int NGRP   = BATCH / 4;         // 4-timestep store groups per batch = 5

typedef const __attribute__((address_space(1))) float g_f;
typedef __attribute__((address_space(3))) float l_f;
typedef float v4f __attribute__((ext_vector_type(4)));

__global__ __launch_bounds__(256)
void lif_fwd(const float* __restrict__ x,
             const float* __restrict__ decay_logit,
             float* __restrict__ out)
{
#pragma clang fp contract(off)   // must NOT fuse mul+add: match numpy rounding
    __shared__ float X[RING][BATCH][H_DIM];   // 143360 B input ring
    __shared__ float S[4][4][4][64];          // 16384 B  [wv][slot][tsub][lane]

    const int tid  = threadIdx.x;        // 0..255: chain h = tid
    const int wv   = tid >> 6;           // wave 0..3
    const int lane = tid & 63;
    const int b    = blockIdx.x;         // batch row

    const float* __restrict__ xrow  = x   + (size_t)b * (T_LEN * H_DIM);
    float* __restrict__       obase = out + (size_t)b * (T_LEN * H_DIM);

    // decay = sigmoid(decay_logit[h]); double precision, rounded once to f32.
    const float d = (float)(1.0 / (1.0 + exp(-(double)decay_logit[tid])));
    float v = 0.0f;
    bool  z = false;

    // packed-store lane mapping: lane l stores t-offset (l>>4), cols 4*(l&15)..+3
    const int tsub = lane >> 4;
    const int hofs = (lane & 15) << 2;

    // Stage slot `bt`: wave wv copies rows [wv*RPW, wv*RPW+RPW). Global src is
    // per-lane (lane*4B float, 16B width); LDS dest wave-uniform (HW adds lane*16).
    auto stage = [&](int bt) {
        const float* gsrc = xrow + (size_t)bt * (BATCH * H_DIM)
                                 + (size_t)(wv * RPW) * H_DIM + lane * 4;
        l_f* lds = (l_f*)&X[bt % RING][wv * RPW][0];
#pragma unroll
        for (int r = 0; r < RPW; ++r)
            __builtin_amdgcn_global_load_lds((g_f*)(gsrc + r * H_DIM),
                                             lds + r * H_DIM, 16, 0, 0);
    };

    // Compute batch j. Global group index G = NGRP*j + g; S slot = G & 3.
    // Group g flushes group G-2 (deferred 2 groups => ds_read latency hidden
    // under ~8 timesteps of VALU chain; flushes cross batch boundaries).
    auto body = [&](int j) {
        const float(*Xj)[H_DIM] = X[j % RING];
#pragma unroll
        for (int g = 0; g < NGRP; ++g) {
            const int G  = NGRP * j + g;
            const int Gf = G - 2;                 // flush target group
            const bool doF = (Gf >= 0);           // false only for j=0, g<2
            v4f pk;
            if (doF)                              // issue LDS read EARLY
                pk = *(const v4f*)&S[wv][Gf & 3][tsub][hofs];
#pragma unroll
            for (int r = 0; r < 4; ++r) {
                float xt = Xj[4 * g + r][tid];    // LDS read, conflict-free
                float vd = v * d;                 // round(v*d)
                float vg = z ? 0.0f : vd;         // *(1-z): exact
                v = vg + xt;                      // round(+x_t)
                z = (v > 0.5f);                   // == (v - 0.5 > 0)
                S[wv][G & 3][r][lane] = z ? 1.0f : 0.0f;
            }
            if (doF) {                            // fire packed store LATE
                const int t = (Gf / NGRP) * BATCH + (Gf % NGRP) * 4 + tsub;
                __builtin_nontemporal_store(pk,
                    (v4f*)(obase + (size_t)t * H_DIM + (wv << 6) + hofs));
            }
        }
    };

    // prologue: fill the ring DEPTH slots deep (30 glds in flight per wave)
    for (int s = 0; s < DEPTH; ++s) stage(s);

    // Per-iter issue order: WAIT(j) -> barrier -> stage(j+DEPTH) -> compute(j).
    // newer-than-glds(j): j<6: >=25 ; 6<=j<=44: =55 ; j>=45: >=30.
#define LIF_ITER(WCNT)                                                        \
    {                                                                         \
        asm volatile("s_waitcnt vmcnt(" #WCNT ")" ::: "memory");              \
        __builtin_amdgcn_sched_barrier(0);                                    \
        __builtin_amdgcn_s_barrier();                                         \
        if (j + DEPTH < NBATCH) stage(j + DEPTH);                             \
        __builtin_amdgcn_sched_barrier(0);                                    \
        body(j);                                                              \
    }

#pragma unroll 1
    for (int j = 0; j < 6; ++j)           LIF_ITER(25)
#pragma unroll 1
    for (int j = 6; j < 45; ++j)          LIF_ITER(55)
#pragma unroll 1
    for (int j = 45; j < NBATCH; ++j)     LIF_ITER(25)
#undef LIF_ITER

    // epilogue: flush the last two groups (G = 248, 249)
#pragma unroll
    for (int G = NGRP * NBATCH - 2; G < NGRP * NBATCH; ++G) {
        v4f pk = *(const v4f*)&S[wv][G & 3][tsub][hofs];
        const int t = (G / NGRP) * BATCH + (G % NGRP) * 4 + tsub;
        __builtin_nontemporal_store(pk,
            (v4f*)(obase + (size_t)t * H_DIM + (wv << 6) + hofs));
    }
}

extern "C" void kernel_launch(void* const* d_in, const int* in_sizes, int n_in,
                              void* d_out, int out_size, void* d_ws, size_t ws_size,
                              hipStream_t stream)
{
    const float* x  = (const float*)d_in[0];         // [B,T,H] f32
    const float* dl = (const float*)d_in[1];         // [H] f32
    float*       o  = (float*)d_out;                 // [B,T,H] f32 spikes

    const int B = in_sizes[0] / (T_LEN * H_DIM);     // 256
    lif_fwd<<<B, 256, 0, stream>>>(x, dl, o);
}

// Round 9
// 81.379 us; speedup vs baseline: 1.3853x; 1.3853x over previous
//
#include <hip/hip_runtime.h>
#include <math.h>

// LIF forward scan: v = v*decay*(1-z_prev) + x_t ; z = (v > 0.5)
// B=256, T=1000, H=256. One block (256 thr = 4 waves) per batch row, but each
// WAVE is fully independent: it owns chains h = wv*64 + lane and a PRIVATE
// 7-slot LDS ring (20 rows x 256B = 5KB/slot). No __syncthreads anywhere.
// global_load_lds stages 4 rows per instr (per-lane global src, linear LDS
// dest); DEPTH=6 prefetch -> 30KB/wave = 120KB/CU reads in flight, self-
// synchronized with counted vmcnt (never drained). Stores are direct 4B/lane
// nt dwords (256B/wave contiguous) -- the R6 pattern that worked; the R7/R8
// LDS store-transpose (DS round trip on the serial chain) is dropped.
constexpr int T_LEN = 1000;
constexpr int H_DIM = 256;
constexpr int SROWS = 20;               // rows per ring slot (5 KB per wave)
constexpr int NSLOT = T_LEN / SROWS;    // 50
constexpr int RING  = 7;                // per-wave ring slots (140 KB total LDS)
constexpr int DEPTH = 6;                // slots prefetched ahead
constexpr int GPS   = SROWS / 4;        // glds per slot (4 rows per 1KB instr) = 5

typedef const __attribute__((address_space(1))) float g_f;
typedef __attribute__((address_space(3))) float l_f;

__global__ __launch_bounds__(256)
void lif_fwd(const float* __restrict__ x,
             const float* __restrict__ decay_logit,
             float* __restrict__ out)
{
#pragma clang fp contract(off)   // must NOT fuse mul+add: match numpy rounding
    __shared__ float X[4][RING][SROWS][64];   // 143360 B, per-wave private rings

    const int tid  = threadIdx.x;        // 0..255: chain h = tid
    const int wv   = tid >> 6;           // wave 0..3
    const int lane = tid & 63;
    const int b    = blockIdx.x;         // batch row

    const float* __restrict__ xrow  = x   + (size_t)b * (T_LEN * H_DIM);
    float* __restrict__       obase = out + (size_t)b * (T_LEN * H_DIM)
                                          + (wv << 6) + lane;

    // decay = sigmoid(decay_logit[h]); double precision, rounded once to f32.
    const float d = (float)(1.0 / (1.0 + exp(-(double)decay_logit[tid])));
    float v = 0.0f;
    bool  z = false;

    // glds lane mapping: lane l covers row r=(l>>4) of a 4-row group, bytes
    // 16*(l&15)..+15 of this wave's 256B column. LDS dest = linear lane*16.
    const size_t srcofs = (size_t)(lane >> 4) * H_DIM + (wv << 6) + ((lane & 15) << 2);

    auto stage = [&](int s) {            // stage slot s (20 rows, 5 glds)
        const float* gsrc = xrow + (size_t)s * (SROWS * H_DIM) + srcofs;
        l_f* lds = (l_f*)&X[wv][s % RING][0][0];
#pragma unroll
        for (int g = 0; g < GPS; ++g)
            __builtin_amdgcn_global_load_lds((g_f*)(gsrc + (size_t)(4 * g) * H_DIM),
                                             lds + g * (4 * 64), 16, 0, 0);
    };

    // prologue: fill ring DEPTH slots deep (30 glds in flight per wave)
#pragma unroll
    for (int s = 0; s < DEPTH; ++s) stage(s);

    // Per-wave in-order vmcnt audit (ops per iter: 5 glds + 20 stores):
    //   j=0: newer-than-glds(0) = 25 (prologue glds 1..5)      -> vmcnt(25)
    //   j=1: newer = 20(prologue) + 5(stage(6)) + 20(stores 0) = 45 -> vmcnt(40)
    //   j>=2: newer >= 62                                       -> vmcnt(62)
#define LIF_ITER(WCNT)                                                        \
    {                                                                         \
        asm volatile("s_waitcnt vmcnt(" #WCNT ")" ::: "memory");              \
        __builtin_amdgcn_sched_barrier(0);                                    \
        if (j + DEPTH < NSLOT) stage(j + DEPTH);                              \
        const float(*Xs)[64] = X[wv][j % RING];                               \
        float* op = obase + (size_t)j * (SROWS * H_DIM);                      \
        _Pragma("unroll")                                                     \
        for (int t = 0; t < SROWS; ++t) {                                     \
            float xt = Xs[t][lane];          /* ds_read_b32, conflict-free */ \
            float vd = v * d;                /* round(v*d)                 */ \
            float vg = z ? 0.0f : vd;        /* *(1-z): exact              */ \
            v = vg + xt;                     /* round(+x_t)                */ \
            z = (v > 0.5f);                  /* == (v - 0.5 > 0)           */ \
            __builtin_nontemporal_store(z ? 1.0f : 0.0f,                      \
                                        op + (size_t)t * H_DIM);              \
        }                                                                     \
    }

    {
        int j = 0;
        LIF_ITER(25)
    }
    {
        int j = 1;
        LIF_ITER(40)
    }
#pragma unroll 1
    for (int j = 2; j < NSLOT; ++j) LIF_ITER(62)
#undef LIF_ITER
}

extern "C" void kernel_launch(void* const* d_in, const int* in_sizes, int n_in,
                              void* d_out, int out_size, void* d_ws, size_t ws_size,
                              hipStream_t stream)
{
    const float* x  = (const float*)d_in[0];         // [B,T,H] f32
    const float* dl = (const float*)d_in[1];         // [H] f32
    float*       o  = (float*)d_out;                 // [B,T,H] f32 spikes

    const int B = in_sizes[0] / (T_LEN * H_DIM);     // 256
    lif_fwd<<<B, 256, 0, stream>>>(x, dl, o);
}

// Round 10
// 80.716 us; speedup vs baseline: 1.3966x; 1.0082x over previous
//
#include <hip/hip_runtime.h>
#include <math.h>

// LIF forward scan: v = v*decay*(1-z_prev) + x_t ; z = (v > 0.5)
// B=256, T=1000, H=256. Producer-consumer wave specialization:
// block = 512 threads = 8 waves. Waves 0-3 COMPUTE (chain h = tid, pure
// LDS+VALU, zero VMEM -> never vmcnt-stalled). Waves 4-7 IO: stage x into a
// 5-slot LDS ring via global_load_lds (1KB/instr, DEPTH=4 -> 80KB/CU reads in
// flight in a store-free vmcnt window) and flush spikes from a ping-pong Z
// LDS buffer as 1KB dwordx4 nt stores (5 store ops/slot/wave instead of 20).
constexpr int T_LEN = 1000;
constexpr int H_DIM = 256;
constexpr int SROWS = 20;               // timestep rows per slot (20 KB)
constexpr int NSLOT = T_LEN / SROWS;    // 50
constexpr int RING  = 5;                // X ring slots (100 KB)
constexpr int DEPTH = 4;                // slots prefetched ahead
constexpr int RPIO  = SROWS / 4;        // rows per IO wave per slot = 5

typedef const __attribute__((address_space(1))) float g_f;
typedef __attribute__((address_space(3))) float l_f;
typedef float v4f __attribute__((ext_vector_type(4)));

__global__ __launch_bounds__(512)
void lif_fwd(const float* __restrict__ x,
             const float* __restrict__ decay_logit,
             float* __restrict__ out)
{
#pragma clang fp contract(off)   // must NOT fuse mul+add: match numpy rounding
    __shared__ float X[RING][SROWS][H_DIM];   // 102400 B input ring
    __shared__ float Z[2][SROWS][H_DIM];      //  40960 B spike ping-pong

    const int tid  = threadIdx.x;        // 0..511
    const int wv   = tid >> 6;           // 0..7
    const int lane = tid & 63;
    const int b    = blockIdx.x;         // batch row

    const float* __restrict__ xrow  = x   + (size_t)b * (T_LEN * H_DIM);
    float* __restrict__       obase = out + (size_t)b * (T_LEN * H_DIM);

    if (wv < 4) {
        // ---------------- compute waves: h = tid, pure LDS + VALU ----------
        const float d = (float)(1.0 / (1.0 + exp(-(double)decay_logit[tid])));
        float v = 0.0f;
        bool  z = false;
#pragma unroll 1
        for (int j = 0; j < NSLOT; ++j) {
            __builtin_amdgcn_s_barrier();        // bar1: X[j] staged (IO waited)
            const float(*Xs)[H_DIM] = X[j % RING];
            float(*Zs)[H_DIM] = Z[j & 1];
#pragma unroll
            for (int t = 0; t < SROWS; ++t) {
                float xt = Xs[t][tid];           // ds_read_b32, conflict-free
                float vd = v * d;                // round(v*d)
                float vg = z ? 0.0f : vd;        // *(1-z): exact
                v = vg + xt;                     // round(+x_t)
                z = (v > 0.5f);                  // == (v - 0.5 > 0)
                Zs[t][tid] = z ? 1.0f : 0.0f;    // ds_write_b32, conflict-free
            }
            // publish Z[j] (raw s_barrier does NOT drain lgkm)
            asm volatile("s_waitcnt lgkmcnt(0)" ::: "memory");
            __builtin_amdgcn_sched_barrier(0);
            __builtin_amdgcn_s_barrier();        // bar2: Z[j] visible
        }
    } else {
        // ---------------- IO waves: stage X ring, flush Z ------------------
        const int w = wv - 4;                    // 0..3

        auto stage = [&](int s) {                // rows [w*5, w*5+5) of slot s
            const float* gsrc = xrow + (size_t)s * (SROWS * H_DIM)
                                     + (size_t)(w * RPIO) * H_DIM + lane * 4;
            l_f* lds = (l_f*)&X[s % RING][w * RPIO][0];
#pragma unroll
            for (int r = 0; r < RPIO; ++r)
                __builtin_amdgcn_global_load_lds((g_f*)(gsrc + (size_t)r * H_DIM),
                                                 lds + r * H_DIM, 16, 0, 0);
        };
        auto flush = [&](int js) {               // spike rows of slot js
            const float(*Zs)[H_DIM] = Z[js & 1];
#pragma unroll
            for (int r = 0; r < RPIO; ++r) {
                v4f pk = *(const v4f*)&Zs[w * RPIO + r][lane * 4];  // ds_read_b128
                __builtin_nontemporal_store(pk,
                    (v4f*)(obase + (size_t)(js * SROWS + w * RPIO + r) * H_DIM
                                 + lane * 4));
            }
        };

        // prologue: 20 glds in flight per IO wave (DEPTH=4 slots)
#pragma unroll
        for (int s = 0; s < DEPTH; ++s) stage(s);

        // In-order vmcnt audit (ops/iter: 5 glds + 5 stores(j>0)):
        // newer-than-glds(j): j=0:15, j=1:15, j=2:25, j=3:25, j=4:30, j>=5:35.
#pragma unroll 1
        for (int j = 0; j < NSLOT; ++j) {
            if      (j < 2)  { asm volatile("s_waitcnt vmcnt(15)" ::: "memory"); }
            else if (j < 4)  { asm volatile("s_waitcnt vmcnt(25)" ::: "memory"); }
            else if (j == 4) { asm volatile("s_waitcnt vmcnt(30)" ::: "memory"); }
            else             { asm volatile("s_waitcnt vmcnt(35)" ::: "memory"); }
            __builtin_amdgcn_sched_barrier(0);
            __builtin_amdgcn_s_barrier();        // bar1: X[j] ready for compute
            if (j + DEPTH < NSLOT) stage(j + DEPTH);   // deepest prefetch first
            __builtin_amdgcn_sched_barrier(0);
            if (j > 0) flush(j - 1);             // Z[j-1] published at bar2(j-1)
            __builtin_amdgcn_sched_barrier(0);
            __builtin_amdgcn_s_barrier();        // bar2: Z[j] visible
        }
        flush(NSLOT - 1);                        // epilogue: last slot's spikes
    }
}

extern "C" void kernel_launch(void* const* d_in, const int* in_sizes, int n_in,
                              void* d_out, int out_size, void* d_ws, size_t ws_size,
                              hipStream_t stream)
{
    const float* x  = (const float*)d_in[0];         // [B,T,H] f32
    const float* dl = (const float*)d_in[1];         // [H] f32
    float*       o  = (float*)d_out;                 // [B,T,H] f32 spikes

    const int B = in_sizes[0] / (T_LEN * H_DIM);     // 256
    lif_fwd<<<B, 512, 0, stream>>>(x, dl, o);
}